// Round 8
// baseline (704.381 us; speedup 1.0000x reference)
//
#include <hip/hip_runtime.h>
#include <hip/hip_bf16.h>
#include <stdint.h>

#define B_ 8
#define C_ 512
#define S_ 2048
#define L_ 8921
#define LTILE 128
#define NLT 70            // real L-tiles; grid pads to 72 for XCD slicing
#define NLTP 72
#define NSC 16            // S / 128
#define ROUNDS 16         // C / 32

using f32x16 = __attribute__((ext_vector_type(16))) float;
using s16x8  = __attribute__((ext_vector_type(8))) short;   // 8 bf16 = 4 VGPRs

static __device__ __forceinline__ unsigned short f2bf(float f) {
    union { float f; uint32_t u; } a; a.f = f;
    uint32_t u = a.u;
    return (unsigned short)((u + 0x7fffu + ((u >> 16) & 1u)) >> 16);   // RTNE
}

// ---- fp32 W (L x C) -> bf16 A-fragment-major layout ----
// frag f = ((lt*4 + wv)*16 + rr)*2 + kstep ; frag = 64 lanes x 16 B.
// lane: row lt*128+wv*32+(lane&31), k = rr*32+kstep*16+(lane>>5)*8+[0,8).
__global__ void cvt_wfrag(const float* __restrict__ src, unsigned short* __restrict__ dst) {
    int gid = blockIdx.x * 256 + threadIdx.x;          // over 72*4*16*2*64
    int lane = gid & 63;
    int f    = gid >> 6;
    int kstep = f & 1;
    int rr    = (f >> 1) & 15;
    int wv    = (f >> 5) & 3;
    int lt    = f >> 7;
    int row = lt * 128 + wv * 32 + (lane & 31);
    if (row > L_ - 1) row = L_ - 1;
    int k0 = rr * 32 + kstep * 16 + (lane >> 5) * 8;
    const float* s = src + (size_t)row * C_ + k0;
    float4 v0 = ((const float4*)s)[0];
    float4 v1 = ((const float4*)s)[1];
    ushort4 o0, o1;
    o0.x = f2bf(v0.x); o0.y = f2bf(v0.y); o0.z = f2bf(v0.z); o0.w = f2bf(v0.w);
    o1.x = f2bf(v1.x); o1.y = f2bf(v1.y); o1.z = f2bf(v1.z); o1.w = f2bf(v1.w);
    ushort4* d = (ushort4*)(dst + (size_t)gid * 8);
    d[0] = o0; d[1] = o1;
}

// ---- encoded (B,C,S) fp32 -> bf16 B-fragment-major layout ----
// frag f = ((bsc*4 + nf)*16 + rr)*2 + kstep, bsc = sc*8 + b.
// lane: s = sc*128 + nf*32 + (lane&31), k = rr*32+kstep*16+(lane>>5)*8+[0,8).
// Reads: for fixed c, 32 lanes hit 128 contiguous bytes of enc; writes: 16 B/lane.
__global__ void cvt_efrag(const float* __restrict__ enc, unsigned short* __restrict__ dst) {
    int tid  = threadIdx.x;
    int lane = tid & 63;
    int f    = blockIdx.x * 4 + (tid >> 6);            // over 128*4*16*2 frags
    int kstep = f & 1;
    int rr    = (f >> 1) & 15;
    int nf    = (f >> 5) & 3;
    int bsc   = f >> 7;
    int b  = bsc & 7;
    int sc = bsc >> 3;
    int s  = sc * 128 + nf * 32 + (lane & 31);
    int c0 = rr * 32 + kstep * 16 + (lane >> 5) * 8;
    const float* src = enc + (size_t)b * C_ * S_ + (size_t)c0 * S_ + s;
    ushort4 o0, o1;
    o0.x = f2bf(src[0 * S_]); o0.y = f2bf(src[1 * S_]);
    o0.z = f2bf(src[2 * S_]); o0.w = f2bf(src[3 * S_]);
    o1.x = f2bf(src[4 * S_]); o1.y = f2bf(src[5 * S_]);
    o1.z = f2bf(src[6 * S_]); o1.w = f2bf(src[7 * S_]);
    ushort4* d = (ushort4*)(dst + (size_t)f * 512 + lane * 8);
    d[0] = o0; d[1] = o1;
}

// ---- fused scores/softmax/value main kernel ----
// Block: 128 L x 128 s, K=512 in 16 rounds of 32. Waves split by m only.
// NO LDS, NO BARRIERS: W and E both loaded global->VGPR from fragment-major
// precomputed layouts (base + lane*16, fully coalesced — R6's gather problem
// solved by layout, not LDS). Ping-pong double buffer, one round prefetch.
// Waves fully independent; E frag addresses identical across the block's 4
// waves -> L1 serves the re-reads. Grid pins lt%8 to XCD x%8 (W L2-resident).
__global__ __launch_bounds__(256) void attn_main(
    const unsigned short* __restrict__ ebtF,
    const unsigned short* __restrict__ wfa,
    const unsigned short* __restrict__ wfc,
    float* __restrict__ pnum, float* __restrict__ pden)
{
    const int tid  = threadIdx.x;
    const int lane = tid & 63;
    const int wave = tid >> 6;

    // x = (bsc*9 + j)*8 + i ; lt = 8j + i (0..71, >=70 pad), bsc = sc*8 + b
    const int x   = blockIdx.x;
    const int i8  = x & 7;
    const int t9  = x >> 3;
    const int jj9 = t9 % 9;
    const int bsc = t9 / 9;
    const int lt  = jj9 * 8 + i8;
    const int b   = bsc & 7;
    const int sc  = bsc >> 3;

    // ---- fragment-major pointers (all loads are base + (rr*2+k)*512 elems) ----
    const unsigned short* waF = wfa + ((size_t)(lt * 4 + wave) * 32) * 512 + lane * 8;
    const unsigned short* wcF = wfc + ((size_t)(lt * 4 + wave) * 32) * 512 + lane * 8;
    const unsigned short* eF0 = ebtF + ((size_t)(bsc * 4 + 0) * 32) * 512 + lane * 8;
    const unsigned short* eF1 = ebtF + ((size_t)(bsc * 4 + 1) * 32) * 512 + lane * 8;
    const unsigned short* eF2 = ebtF + ((size_t)(bsc * 4 + 2) * 32) * 512 + lane * 8;
    const unsigned short* eF3 = ebtF + ((size_t)(bsc * 4 + 3) * 32) * 512 + lane * 8;

    struct RND { s16x8 wa0, wa1, wc0, wc1, e[4][2]; };
    auto loadRound = [&](int rr, RND& r) {
        const int co = rr * 1024;
        r.wa0 = *(const s16x8*)(waF + co);
        r.wa1 = *(const s16x8*)(waF + co + 512);
        r.wc0 = *(const s16x8*)(wcF + co);
        r.wc1 = *(const s16x8*)(wcF + co + 512);
        r.e[0][0] = *(const s16x8*)(eF0 + co);  r.e[0][1] = *(const s16x8*)(eF0 + co + 512);
        r.e[1][0] = *(const s16x8*)(eF1 + co);  r.e[1][1] = *(const s16x8*)(eF1 + co + 512);
        r.e[2][0] = *(const s16x8*)(eF2 + co);  r.e[2][1] = *(const s16x8*)(eF2 + co + 512);
        r.e[3][0] = *(const s16x8*)(eF3 + co);  r.e[3][1] = *(const s16x8*)(eF3 + co + 512);
    };

    f32x16 accS[4], accV[4];
    #pragma unroll
    for (int nf = 0; nf < 4; ++nf)
        #pragma unroll
        for (int r = 0; r < 16; ++r) { accS[nf][r] = 0.f; accV[nf][r] = 0.f; }

    auto mfmaRound = [&](const RND& rd) {
        #pragma unroll
        for (int nf = 0; nf < 4; ++nf) {
            accS[nf] = __builtin_amdgcn_mfma_f32_32x32x16_bf16(rd.wa0, rd.e[nf][0], accS[nf], 0, 0, 0);
            accV[nf] = __builtin_amdgcn_mfma_f32_32x32x16_bf16(rd.wc0, rd.e[nf][0], accV[nf], 0, 0, 0);
        }
        #pragma unroll
        for (int nf = 0; nf < 4; ++nf) {
            accS[nf] = __builtin_amdgcn_mfma_f32_32x32x16_bf16(rd.wa1, rd.e[nf][1], accS[nf], 0, 0, 0);
            accV[nf] = __builtin_amdgcn_mfma_f32_32x32x16_bf16(rd.wc1, rd.e[nf][1], accV[nf], 0, 0, 0);
        }
    };

    RND r0, r1;
    loadRound(0, r0);
    for (int rr2 = 0; rr2 < ROUNDS / 2; ++rr2) {
        loadRound(2 * rr2 + 1, r1);
        mfmaRound(r0);
        if (rr2 + 1 < ROUNDS / 2) loadRound(2 * rr2 + 2, r0);
        mfmaRound(r1);
    }

    // ---- epilogue: exp + s-reduction. C/D 32x32 layout: col = lane&31 (s),
    // row = (r&3) + 8*(r>>2) + 4*(lane>>5). |score|<~3.5 -> exp safe, no max.
    const int h = lane >> 5;
    float numA[16], denA[16];
    #pragma unroll
    for (int r = 0; r < 16; ++r) { numA[r] = 0.f; denA[r] = 0.f; }
    #pragma unroll
    for (int nf = 0; nf < 4; ++nf)
        #pragma unroll
        for (int r = 0; r < 16; ++r) {
            float e = __expf(accS[nf][r]);
            denA[r] += e;
            numA[r] += e * accV[nf][r];
        }
    if (lt < NLT) {
        const size_t obase = ((size_t)((b * NLT + lt) * NSC + sc)) * LTILE;
        #pragma unroll
        for (int r = 0; r < 16; ++r) {
            float n = numA[r], d = denA[r];
            n += __shfl_xor(n, 1);   d += __shfl_xor(d, 1);
            n += __shfl_xor(n, 2);   d += __shfl_xor(d, 2);
            n += __shfl_xor(n, 4);   d += __shfl_xor(d, 4);
            n += __shfl_xor(n, 8);   d += __shfl_xor(d, 8);
            n += __shfl_xor(n, 16);  d += __shfl_xor(d, 16);
            if ((lane & 31) == 0) {
                int row = wave * 32 + (r & 3) + 8 * (r >> 2) + 4 * h;
                pnum[obase + row] = n;
                pden[obase + row] = d;
            }
        }
    }
}

// ---- combine s-chunk partials, divide, add b_cls ----
__global__ void finalize(const float* __restrict__ pnum, const float* __restrict__ pden,
                         const float* __restrict__ bcls, float* __restrict__ out) {
    int gid = blockIdx.x * 256 + threadIdx.x;
    if (gid >= B_ * L_) return;
    int b = gid / L_, l = gid - b * L_;
    int lt = l >> 7, row = l & 127;
    float n = 0.f, d = 0.f;
    #pragma unroll
    for (int s = 0; s < NSC; ++s) {
        size_t idx = ((size_t)((b * NLT + lt) * NSC + s)) * LTILE + row;
        n += pnum[idx];
        d += pden[idx];
    }
    out[gid] = n / d + bcls[l];
}

extern "C" void kernel_launch(void* const* d_in, const int* in_sizes, int n_in,
                              void* d_out, int out_size, void* d_ws, size_t ws_size,
                              hipStream_t stream) {
    (void)in_sizes; (void)n_in; (void)out_size; (void)ws_size;
    const float* enc  = (const float*)d_in[0];
    const float* Wa   = (const float*)d_in[1];
    // d_in[2] = b_attn: cancels in softmax over S — unused.
    const float* Wc   = (const float*)d_in[3];
    const float* bcls = (const float*)d_in[4];

    unsigned char* ws = (unsigned char*)d_ws;
    const size_t oEbt = 0;                          // B*S*C*2  = 16,777,216
    const size_t oWa  = oEbt + 16777216;            // 72*128KB =  9,437,184
    const size_t oWc  = oWa + 9437184;
    const size_t oPn  = oWc + 9437184;              // 8*70*16*128*4 = 4,587,520
    const size_t oPd  = oPn + 4587520;              // total ~44.8 MB

    unsigned short* ebtF = (unsigned short*)(ws + oEbt);
    unsigned short* wfa  = (unsigned short*)(ws + oWa);
    unsigned short* wfc  = (unsigned short*)(ws + oWc);
    float* pnum = (float*)(ws + oPn);
    float* pden = (float*)(ws + oPd);

    const int wThreads = NLTP * 4 * ROUNDS * 2 * 64;    // 589,824
    cvt_wfrag<<<wThreads / 256, 256, 0, stream>>>(Wa, wfa);
    cvt_wfrag<<<wThreads / 256, 256, 0, stream>>>(Wc, wfc);
    cvt_efrag<<<(128 * 4 * ROUNDS * 2) / 4, 256, 0, stream>>>(enc, ebtF);
    attn_main<<<128 * 9 * 8, 256, 0, stream>>>(ebtF, wfa, wfc, pnum, pden);
    finalize<<<(B_ * L_ + 255) / 256, 256, 0, stream>>>(pnum, pden, bcls, (float*)d_out);
}